// Round 5
// baseline (1848.866 us; speedup 1.0000x reference)
//
#include <hip/hip_runtime.h>

#define DHN 512
#define TN  1024
#define BN  64
#define CH  32      // noise-staging chunk (steps)

typedef unsigned short u16;
typedef unsigned int   u32;

static __device__ __forceinline__ float sigm(float x) {
  return 1.0f / (1.0f + __expf(-x));
}

#if defined(__has_builtin)
#if __has_builtin(__builtin_amdgcn_sdot4)
#define HAVE_SDOT4 1
#endif
#endif

// All packed bytes are in [0,127]: signed == unsigned dot.
static __device__ __forceinline__ int dot4(int a, int b, int c) {
#ifdef HAVE_SDOT4
  return __builtin_amdgcn_sdot4(a, b, c, false);
#else
  c += (int)(signed char)(a)       * (int)(signed char)(b);
  c += (int)(signed char)(a >> 8)  * (int)(signed char)(b >> 8);
  c += (int)(signed char)(a >> 16) * (int)(signed char)(b >> 16);
  c += (int)(signed char)(a >> 24) * (int)(signed char)(b >> 24);
  return c;
#endif
}

// Persistent RNN: one block per batch chain (64 blocks). All inputs FP32,
// all outputs FP32. w = |_w @ diag(+-1)| = |_w| elementwise -> prologue
// matmul is free. Thread h owns row h of W: loads the fp32 row once,
// quantizes to i8 with a per-row scale into 128 VGPRs. r (in (0,1)) is
// quantized to i8 scale-127 and broadcast from double-buffered LDS. Noise
// staged per 32-step chunk in LDS. xs accumulated 8 steps in registers,
// flushed as aligned float4 stores.
__global__ __launch_bounds__(512, 2) void k_rnn(
    const float* __restrict__ u, const float* __restrict__ r0,
    const float* __restrict__ noise, const float* __restrict__ win,
    const float* __restrict__ taus, const float* __restrict__ wmat,
    float* __restrict__ xs) {
  __shared__ float u_lds[TN];           // 4 KB
  __shared__ float nz_lds[CH * DHN];    // 64 KB
  __shared__ int4  rbuf[2][DHN / 16];   // 1 KB, i8 r double-buffered

  const int h = threadIdx.x;
  const int b = blockIdx.x;
  const float* wrow = wmat + h * DHN;   // row h of _w (2 KB, 16B-aligned)

  // pass 1: row absmax of |_w[h,:]|
  float rmax = 1e-30f;
#pragma unroll 8
  for (int k = 0; k < 128; ++k) {
    float4 v = *(const float4*)(wrow + 4 * k);
    rmax = fmaxf(rmax, fabsf(v.x));
    rmax = fmaxf(rmax, fabsf(v.y));
    rmax = fmaxf(rmax, fabsf(v.z));
    rmax = fmaxf(rmax, fabsf(v.w));
  }
  const float qs = 127.0f / rmax;

  // pass 2: quantize row into 128 VGPRs; w[k] bytes 0..3 = |w| cols 4k..4k+3
  int w[128];
#pragma unroll
  for (int k = 0; k < 128; ++k) {
    float4 v = *(const float4*)(wrow + 4 * k);
    int q0 = __float2int_rn(fabsf(v.x) * qs);
    int q1 = __float2int_rn(fabsf(v.y) * qs);
    int q2 = __float2int_rn(fabsf(v.z) * qs);
    int q3 = __float2int_rn(fabsf(v.w) * qs);
    q0 = min(max(q0, 0), 127); q1 = min(max(q1, 0), 127);
    q2 = min(max(q2, 0), 127); q3 = min(max(q3, 0), 127);
    w[k] = q0 | (q1 << 8) | (q2 << 16) | (q3 << 24);
  }

  const float alpha  = 1.0f / taus[h];          // dt = 1
  const float beta   = 1.0f - alpha;
  const float win_h  = win[h];
  const float dscale = rmax * alpha * (1.0f / 16129.0f);  // rmax/127^2 * alpha
  float s = r0[b * DHN + h];                    // x_in at t=0 is RAW r0

  for (int i = h; i < TN; i += DHN) u_lds[i] = u[b * TN + i];
  ((signed char*)rbuf)[h] =
      (signed char)__float2int_rn(sigm(s) * 127.0f);      // r for t=0

  const float* np = noise + (size_t)b * DHN + h;          // noise[t][b][h]
  float* xrow = xs + ((size_t)b * DHN + h) * TN;          // xs[b][h][t]

#pragma unroll 1
  for (int tc = 0; tc < TN; tc += CH) {
    __syncthreads();                    // prior chunk consumed (also covers
                                        // the init writes above on tc==0)
#pragma unroll
    for (int k = 0; k < CH; ++k)        // coalesced across threads per k
      nz_lds[k * DHN + h] = np[(size_t)(tc + k) * (BN * DHN)];
    __syncthreads();

#pragma unroll 1
    for (int t8 = 0; t8 < CH; t8 += 8) {
      float xv[8];
#pragma unroll
      for (int e = 0; e < 8; ++e) {
        const int t  = tc + t8 + e;
        const int tk = t8 + e;
        const int4* rb = &rbuf[t & 1][0];
        int a0 = 0, a1 = 0, a2 = 0, a3 = 0;
#pragma unroll
        for (int j = 0; j < 32; ++j) {
          int4 rv = rb[j];              // broadcast ds_read_b128
          a0 = dot4(w[4 * j + 0], rv.x, a0);
          a1 = dot4(w[4 * j + 1], rv.y, a1);
          a2 = dot4(w[4 * j + 2], rv.z, a2);
          a3 = dot4(w[4 * j + 3], rv.w, a3);
        }
        float x = beta * s + (float)((a0 + a1) + (a2 + a3)) * dscale
                + win_h * u_lds[t] + 0.1f * nz_lds[tk * DHN + h];
        x = fminf(fmaxf(x, -40.0f), 40.0f);   // never binds on sane values
        xv[e] = x;
        float sp = sigm(x);                   // next x_in = sigmoid(x_new)
        ((signed char*)rbuf)[((t + 1) & 1) * DHN + h] =
            (signed char)__float2int_rn(sigm(sp) * 127.0f);  // next r
        s = sp;
        __syncthreads();
      }
      float4 p0 = {xv[0], xv[1], xv[2], xv[3]};
      float4 p1 = {xv[4], xv[5], xv[6], xv[7]};
      *(float4*)(xrow + tc + t8)     = p0;    // 16B aligned
      *(float4*)(xrow + tc + t8 + 4) = p1;
    }
  }
}

// out[b,t] = bias + sum_h wout[h]*sigmoid(xs[b,h,t]); recomputed from stored
// fp32 xs (exact same values the main kernel produced).
__global__ __launch_bounds__(256) void k_out(
    const float* __restrict__ xs, const float* __restrict__ wout,
    const float* __restrict__ bias, float* __restrict__ outp) {
  __shared__ float wl[DHN];
  int b = blockIdx.x >> 2;
  int t = ((blockIdx.x & 3) << 8) | threadIdx.x;
  for (int i = threadIdx.x; i < DHN; i += 256) wl[i] = wout[i];
  __syncthreads();
  const float* col = xs + (size_t)b * DHN * TN + t;
  float acc = bias[0];
#pragma unroll 4
  for (int hh = 0; hh < DHN; ++hh)      // consecutive t across lanes: coalesced
    acc += wl[hh] * sigm(col[(size_t)hh * TN]);
  outp[b * TN + t] = acc;
}

extern "C" void kernel_launch(void* const* d_in, const int* in_sizes, int n_in,
                              void* d_out, int out_size, void* d_ws, size_t ws_size,
                              hipStream_t stream) {
  const float* u     = (const float*)d_in[0];   // (64,1024,1) fp32
  const float* r0    = (const float*)d_in[1];   // (64,512,1)  fp32
  const float* noise = (const float*)d_in[2];   // (1024,64,512,1) fp32
  const float* win   = (const float*)d_in[3];   // (512,1) fp32
  // d_in[4] = m: diag +-1, cancelled by abs() -> unused
  const float* wout  = (const float*)d_in[5];   // (1,512) fp32
  const float* w_    = (const float*)d_in[6];   // (512,512) fp32
  const float* taus  = (const float*)d_in[7];   // (512,1) fp32
  const float* bias  = (const float*)d_in[8];   // (1,1) fp32

  float* outp = (float*)d_out;              // outputs (64,1024,1) fp32
  float* xs   = outp + BN * TN;             // xs_out (64,512,1024) fp32

  k_rnn<<<BN, DHN, 0, stream>>>(u, r0, noise, win, taus, w_, xs);
  k_out<<<256, 256, 0, stream>>>(xs, wout, bias, outp);
}